// Round 3
// baseline (162.844 us; speedup 1.0000x reference)
//
#include <hip/hip_runtime.h>
#include <hip/hip_bf16.h>

#define B_ 4
#define T_ 2048
#define E_ 1024
#define H_ 16
#define D_ 64
#define Mtot 8192
#define N2 2048
#define K_ 1024

typedef __attribute__((ext_vector_type(8))) short short8;
typedef __attribute__((ext_vector_type(4))) float f32x4;
using bf16 = __hip_bfloat16;

__device__ __forceinline__ void async_copy16(const void* g, void* l) {
  __builtin_amdgcn_global_load_lds(
      (const __attribute__((address_space(1))) unsigned int*)g,
      (__attribute__((address_space(3))) unsigned int*)l, 16, 0, 0);
}

// ---------------- cast fp32 -> bf16 (vectorized) ----------------
__global__ void cast_f32_to_bf16(const float* __restrict__ in, ushort* __restrict__ out, int n4) {
  int stride = gridDim.x * blockDim.x;
  for (int i = blockIdx.x * blockDim.x + threadIdx.x; i < n4; i += stride) {
    float4 v = reinterpret_cast<const float4*>(in)[i];
    bf16 a = __float2bfloat16(v.x), b = __float2bfloat16(v.y);
    bf16 c = __float2bfloat16(v.z), d = __float2bfloat16(v.w);
    ushort4 o = make_ushort4(*(ushort*)&a, *(ushort*)&b, *(ushort*)&c, *(ushort*)&d);
    reinterpret_cast<ushort4*>(out)[i] = o;
  }
}

// ---------------- lift GEMM (m97 structure): C[m][f] = sum_e g[m][e]*Wl[f][e] ----
// 128x128 tile, BK=64, global_load_lds width=16, linear LDS + XOR-swizzled reads
// with pre-swizzled per-lane global sources (both-sides involution).
#define GBK 64

__launch_bounds__(256)
__global__ void lift_gemm(const bf16* __restrict__ A, const bf16* __restrict__ Bm,
                          bf16* __restrict__ qh, bf16* __restrict__ kh) {
  __shared__ __align__(16) bf16 sA[128 * GBK];  // 16KB, physical (swizzled) layout
  __shared__ __align__(16) bf16 sB[128 * GBK];
  const int m0 = blockIdx.x * 128;
  const int n0 = blockIdx.y * 128;
  const int tid = threadIdx.x;
  const int lane = tid & 63, w = tid >> 6;
  const int wr = w >> 1, wc = w & 1;
  const int lr = lane & 15, lg = lane >> 4;

  f32x4 acc[4][4];
#pragma unroll
  for (int i = 0; i < 4; ++i)
#pragma unroll
    for (int j = 0; j < 4; ++j) acc[i][j] = (f32x4)(0.0f);

  const char* Ab = (const char*)A;
  const char* Bb = (const char*)Bm;

  for (int k0 = 0; k0 < K_; k0 += GBK) {
    __syncthreads();
    // stage: each wave issues 4 x 1KB for A and for B. LDS dest is linear
    // (wave-uniform base + lane*16); global src is inverse-swizzled per lane.
#pragma unroll
    for (int it = 0; it < 4; ++it) {
      const int o = ((w * 4 + it) << 10) | (lane << 4);       // physical LDS byte
      const int lin = o ^ (((o >> 7) & 7) << 4);              // logical [row][col]
      const int r = lin >> 7, cb = lin & 127;
      const size_t gof = ((size_t)(m0 + r) * K_ + k0) * 2 + cb;
      const size_t gof_b = ((size_t)(n0 + r) * K_ + k0) * 2 + cb;
      async_copy16(Ab + gof, (char*)sA + ((w * 4 + it) << 10));
      async_copy16(Bb + gof_b, (char*)sB + ((w * 4 + it) << 10));
    }
    __syncthreads();

#pragma unroll
    for (int h = 0; h < 2; ++h) {  // two K=32 halves
      short8 af[4], bfr[4];
#pragma unroll
      for (int i = 0; i < 4; ++i) {
        int row = wr * 64 + i * 16 + lr;
        int off = (row << 7) + (h << 6) + (lg << 4);
        off ^= ((row & 7) << 4);
        af[i] = *(const short8*)((const char*)sA + off);
      }
#pragma unroll
      for (int j = 0; j < 4; ++j) {
        int row = wc * 64 + j * 16 + lr;
        int off = (row << 7) + (h << 6) + (lg << 4);
        off ^= ((row & 7) << 4);
        bfr[j] = *(const short8*)((const char*)sB + off);
      }
#pragma unroll
      for (int i = 0; i < 4; ++i)
#pragma unroll
        for (int j = 0; j < 4; ++j)
          acc[i][j] = __builtin_amdgcn_mfma_f32_16x16x32_bf16(af[i], bfr[j], acc[i][j], 0, 0, 0);
    }
  }

  // epilogue: scatter bf16 into qh/kh [b][h][t][d]
#pragma unroll
  for (int i = 0; i < 4; ++i) {
#pragma unroll
    for (int j = 0; j < 4; ++j) {
#pragma unroll
      for (int r = 0; r < 4; ++r) {
        int m = m0 + wr * 64 + i * 16 + lg * 4 + r;
        int f = n0 + wc * 64 + j * 16 + lr;
        bf16 bv = __float2bfloat16(acc[i][j][r]);
        int b = m >> 11, t = m & (T_ - 1);
        int hh = (f & (E_ - 1)) >> 6, d = f & (D_ - 1);
        bf16* dst = (f < E_) ? qh : kh;
        dst[((((size_t)b * H_ + hh) * T_) + t) * D_ + d] = bv;
      }
    }
  }
}

// ---------------- causal LSE: no-max sum-exp, reg-double-buffered K prefetch ----
// 1-D grid of 1024 blocks, bijective XCD swizzle so each XCD owns 8 bh values
// (K panel 8x256KB = 2MB resident in its 4MB L2). 4 waves/block, 32 q-rows each.
#define LSE_QT 128

#define LOAD_TILE(buf, kt_)                                                        \
  do {                                                                             \
    const bf16* kp_ = kbase + (size_t)(kt_) * 64 * D_;                             \
    _Pragma("unroll") for (int j = 0; j < 4; ++j) {                                \
      buf[2 * j]     = *(const short8*)&kp_[(size_t)(j * 16 + lr) * D_ + lg * 8];  \
      buf[2 * j + 1] = *(const short8*)&kp_[(size_t)(j * 16 + lr) * D_ + 32 + lg * 8]; \
    }                                                                              \
  } while (0)

#define COMPUTE_TILE(buf)                                                          \
  do {                                                                             \
    f32x4 s[2][4];                                                                 \
    _Pragma("unroll") for (int f = 0; f < 2; ++f)                                  \
      _Pragma("unroll") for (int j = 0; j < 4; ++j) s[f][j] = (f32x4)(0.0f);       \
    _Pragma("unroll") for (int j = 0; j < 4; ++j) {                                \
      s[0][j] = __builtin_amdgcn_mfma_f32_16x16x32_bf16(qf[0][0], buf[2 * j], s[0][j], 0, 0, 0); \
      s[0][j] = __builtin_amdgcn_mfma_f32_16x16x32_bf16(qf[0][1], buf[2 * j + 1], s[0][j], 0, 0, 0); \
      s[1][j] = __builtin_amdgcn_mfma_f32_16x16x32_bf16(qf[1][0], buf[2 * j], s[1][j], 0, 0, 0); \
      s[1][j] = __builtin_amdgcn_mfma_f32_16x16x32_bf16(qf[1][1], buf[2 * j + 1], s[1][j], 0, 0, 0); \
    }                                                                              \
    _Pragma("unroll") for (int f = 0; f < 2; ++f)                                  \
      _Pragma("unroll") for (int j = 0; j < 4; ++j)                                \
        _Pragma("unroll") for (int r = 0; r < 4; ++r) l[f][r] += __expf(s[f][j][r]); \
  } while (0)

__launch_bounds__(256)
__global__ void attn_lse(const bf16* __restrict__ qh, const bf16* __restrict__ kh,
                         float* __restrict__ lse) {
  const int bid = blockIdx.x;
  const int sw = ((bid & 7) << 7) | (bid >> 3);  // bijective XCD swizzle (1024 = 8*128)
  const int bh = sw >> 4;
  const int qt = 15 - (sw & 15);                 // heavy blocks first within each XCD
  const int tid = threadIdx.x;
  const int lane = tid & 63, w = tid >> 6;
  const int lr = lane & 15, lg = lane >> 4;
  const int qbase = qt * LSE_QT + w * 32;

  const bf16* qp = qh + ((size_t)bh * T_ + qbase) * D_;
  short8 qf[2][2];
#pragma unroll
  for (int f = 0; f < 2; ++f)
#pragma unroll
    for (int h = 0; h < 2; ++h)
      qf[f][h] = *(const short8*)&qp[(size_t)(f * 16 + lr) * D_ + h * 32 + lg * 8];

  float l[2][4];
#pragma unroll
  for (int f = 0; f < 2; ++f)
#pragma unroll
    for (int r = 0; r < 4; ++r) l[f][r] = 0.0f;

  const bf16* kbase = kh + (size_t)bh * T_ * D_;
  const int nfull = qbase >> 6;  // tiles 0..nfull-1 unmasked; tile nfull is diagonal

  short8 bufA[8], bufB[8];
  if (nfull > 0) LOAD_TILE(bufA, 0);
  if (nfull > 1) LOAD_TILE(bufB, 1);

  int kt = 0;
  for (; kt + 2 < nfull; kt += 2) {
    COMPUTE_TILE(bufA);            // tile kt
    LOAD_TILE(bufA, kt + 2);       // prefetch (kt+2 <= nfull, always valid memory)
    COMPUTE_TILE(bufB);            // tile kt+1
    LOAD_TILE(bufB, kt + 3);       // kt+3 <= nfull, valid
  }
  if (kt < nfull) COMPUTE_TILE(bufA);
  if (kt + 1 < nfull) COMPUTE_TILE(bufB);

  // diagonal (partial) tile
  {
    const int dkt = nfull;
    LOAD_TILE(bufA, dkt);
    f32x4 s[2][4];
#pragma unroll
    for (int f = 0; f < 2; ++f)
#pragma unroll
      for (int j = 0; j < 4; ++j) s[f][j] = (f32x4)(0.0f);
#pragma unroll
    for (int j = 0; j < 4; ++j) {
      s[0][j] = __builtin_amdgcn_mfma_f32_16x16x32_bf16(qf[0][0], bufA[2 * j], s[0][j], 0, 0, 0);
      s[0][j] = __builtin_amdgcn_mfma_f32_16x16x32_bf16(qf[0][1], bufA[2 * j + 1], s[0][j], 0, 0, 0);
      s[1][j] = __builtin_amdgcn_mfma_f32_16x16x32_bf16(qf[1][0], bufA[2 * j], s[1][j], 0, 0, 0);
      s[1][j] = __builtin_amdgcn_mfma_f32_16x16x32_bf16(qf[1][1], bufA[2 * j + 1], s[1][j], 0, 0, 0);
    }
#pragma unroll
    for (int f = 0; f < 2; ++f)
#pragma unroll
      for (int j = 0; j < 4; ++j)
#pragma unroll
        for (int r = 0; r < 4; ++r) {
          int qrow = qbase + f * 16 + lg * 4 + r;
          int key = dkt * 64 + j * 16 + lr;
          float a = (key <= qrow) ? s[f][j][r] : -INFINITY;
          l[f][r] += __expf(a);  // __expf(-inf) == 0
        }
  }

  // cross-lane (lr) reduce and store
#pragma unroll
  for (int f = 0; f < 2; ++f)
#pragma unroll
    for (int r = 0; r < 4; ++r) {
      float v = l[f][r];
      v += __shfl_xor(v, 1);
      v += __shfl_xor(v, 2);
      v += __shfl_xor(v, 4);
      v += __shfl_xor(v, 8);
      if (lr == 0)
        lse[(size_t)bh * T_ + qbase + f * 16 + lg * 4 + r] = __logf(v);
    }
}

// ---------------- final: out[b,t] = sum_h lse[b,h,t] * cw[h] ----------------
__global__ void proj_out(const float* __restrict__ lse, const float* __restrict__ Wp,
                         float* __restrict__ out) {
  __shared__ float cw[H_];
  int tid = threadIdx.x;
  if (tid < H_) {
    float s = 0.0f;
    for (int g = 0; g < H_; ++g) s += Wp[g * H_ + tid];
    cw[tid] = s;
  }
  __syncthreads();
  int idx = blockIdx.x * blockDim.x + tid;  // b*T + t
  int b = idx >> 11, t = idx & (T_ - 1);
  float s = 0.0f;
#pragma unroll
  for (int h = 0; h < H_; ++h) s += lse[((size_t)(b * H_ + h) * T_) + t] * cw[h];
  out[idx] = s;
}

// ---------------- launch ----------------
extern "C" void kernel_launch(void* const* d_in, const int* in_sizes, int n_in,
                              void* d_out, int out_size, void* d_ws, size_t ws_size,
                              hipStream_t stream) {
  (void)in_sizes; (void)n_in; (void)out_size; (void)ws_size;
  const float* g  = (const float*)d_in[0];   // [B,T,E] fp32
  const float* Wl = (const float*)d_in[1];   // [2E,E] fp32
  const float* Wp = (const float*)d_in[2];   // [H,H] fp32
  float* out = (float*)d_out;                // [B*T] fp32

  char* ws = (char*)d_ws;
  size_t off = 0;
  bf16* g_bf  = (bf16*)(ws + off); off += (size_t)Mtot * K_ * 2;
  bf16* wl_bf = (bf16*)(ws + off); off += (size_t)N2 * K_ * 2;
  bf16* qh    = (bf16*)(ws + off); off += (size_t)B_ * H_ * T_ * D_ * 2;
  bf16* kh    = (bf16*)(ws + off); off += (size_t)B_ * H_ * T_ * D_ * 2;
  float* lse  = (float*)(ws + off);

  cast_f32_to_bf16<<<2048, 256, 0, stream>>>(g,  (ushort*)g_bf,  (Mtot * K_) / 4);
  cast_f32_to_bf16<<<512,  256, 0, stream>>>(Wl, (ushort*)wl_bf, (N2 * K_) / 4);

  lift_gemm<<<dim3(Mtot / 128, N2 / 128), 256, 0, stream>>>(g_bf, wl_bf, qh, kh);

  attn_lse<<<1024, 256, 0, stream>>>(qh, kh, lse);

  proj_out<<<(B_ * T_) / 256, 256, 0, stream>>>(lse, Wp, out);
}

// Round 4
// 137.905 us; speedup vs baseline: 1.1808x; 1.1808x over previous
//
#include <hip/hip_runtime.h>
#include <hip/hip_bf16.h>

#define B_ 4
#define T_ 2048
#define E_ 1024
#define H_ 16
#define D_ 64
#define Mtot 8192
#define N2 2048
#define K_ 1024
#define PS_ (B_ * H_ * T_)   // one psum plane

typedef __attribute__((ext_vector_type(8))) short short8;
typedef __attribute__((ext_vector_type(4))) float f32x4;
using bf16 = __hip_bfloat16;

__device__ __forceinline__ void async_copy16(const void* g, void* l) {
  __builtin_amdgcn_global_load_lds(
      (const __attribute__((address_space(1))) unsigned int*)g,
      (__attribute__((address_space(3))) unsigned int*)l, 16, 0, 0);
}

// ---------------- cast fp32 -> bf16 (vectorized) ----------------
__global__ void cast_f32_to_bf16(const float* __restrict__ in, ushort* __restrict__ out, int n4) {
  int stride = gridDim.x * blockDim.x;
  for (int i = blockIdx.x * blockDim.x + threadIdx.x; i < n4; i += stride) {
    float4 v = reinterpret_cast<const float4*>(in)[i];
    bf16 a = __float2bfloat16(v.x), b = __float2bfloat16(v.y);
    bf16 c = __float2bfloat16(v.z), d = __float2bfloat16(v.w);
    ushort4 o = make_ushort4(*(ushort*)&a, *(ushort*)&b, *(ushort*)&c, *(ushort*)&d);
    reinterpret_cast<ushort4*>(out)[i] = o;
  }
}

// ---------------- lift GEMM (m97 structure, kept from R3) ----------------
#define GBK 64

__launch_bounds__(256)
__global__ void lift_gemm(const bf16* __restrict__ A, const bf16* __restrict__ Bm,
                          bf16* __restrict__ qh, bf16* __restrict__ kh) {
  __shared__ __align__(16) bf16 sA[128 * GBK];
  __shared__ __align__(16) bf16 sB[128 * GBK];
  const int m0 = blockIdx.x * 128;
  const int n0 = blockIdx.y * 128;
  const int tid = threadIdx.x;
  const int lane = tid & 63, w = tid >> 6;
  const int wr = w >> 1, wc = w & 1;
  const int lr = lane & 15, lg = lane >> 4;

  f32x4 acc[4][4];
#pragma unroll
  for (int i = 0; i < 4; ++i)
#pragma unroll
    for (int j = 0; j < 4; ++j) acc[i][j] = (f32x4)(0.0f);

  const char* Ab = (const char*)A;
  const char* Bb = (const char*)Bm;

  for (int k0 = 0; k0 < K_; k0 += GBK) {
    __syncthreads();
#pragma unroll
    for (int it = 0; it < 4; ++it) {
      const int o = ((w * 4 + it) << 10) | (lane << 4);
      const int lin = o ^ (((o >> 7) & 7) << 4);
      const int r = lin >> 7, cb = lin & 127;
      const size_t gof = ((size_t)(m0 + r) * K_ + k0) * 2 + cb;
      const size_t gof_b = ((size_t)(n0 + r) * K_ + k0) * 2 + cb;
      async_copy16(Ab + gof, (char*)sA + ((w * 4 + it) << 10));
      async_copy16(Bb + gof_b, (char*)sB + ((w * 4 + it) << 10));
    }
    __syncthreads();

#pragma unroll
    for (int h = 0; h < 2; ++h) {
      short8 af[4], bfr[4];
#pragma unroll
      for (int i = 0; i < 4; ++i) {
        int row = wr * 64 + i * 16 + lr;
        int off = (row << 7) + (h << 6) + (lg << 4);
        off ^= ((row & 7) << 4);
        af[i] = *(const short8*)((const char*)sA + off);
      }
#pragma unroll
      for (int j = 0; j < 4; ++j) {
        int row = wc * 64 + j * 16 + lr;
        int off = (row << 7) + (h << 6) + (lg << 4);
        off ^= ((row & 7) << 4);
        bfr[j] = *(const short8*)((const char*)sB + off);
      }
#pragma unroll
      for (int i = 0; i < 4; ++i)
#pragma unroll
        for (int j = 0; j < 4; ++j)
          acc[i][j] = __builtin_amdgcn_mfma_f32_16x16x32_bf16(af[i], bfr[j], acc[i][j], 0, 0, 0);
    }
  }

#pragma unroll
  for (int i = 0; i < 4; ++i) {
#pragma unroll
    for (int j = 0; j < 4; ++j) {
#pragma unroll
      for (int r = 0; r < 4; ++r) {
        int m = m0 + wr * 64 + i * 16 + lg * 4 + r;
        int f = n0 + wc * 64 + j * 16 + lr;
        bf16 bv = __float2bfloat16(acc[i][j][r]);
        int b = m >> 11, t = m & (T_ - 1);
        int hh = (f & (E_ - 1)) >> 6, d = f & (D_ - 1);
        bf16* dst = (f < E_) ? qh : kh;
        dst[((((size_t)b * H_ + hh) * T_) + t) * D_ + d] = bv;
      }
    }
  }
}

// ---------------- causal LSE partial sums: 4-way strided KV split ----------------
// Grid 4096 = (qt desc) x (bh) x (s in 0..3). Block = 4 waves, wave owns 32 q rows.
// Wave computes sum_{kt ≡ s (mod 4), kt < nfull} sum-exp, plus diagonal if s==nfull%4.
// Partials stored to psum[s][bh][t]; proj_out combines with log().
#define LSE_QT 128

__launch_bounds__(256)
__global__ void attn_lse(const bf16* __restrict__ qh, const bf16* __restrict__ kh,
                         float* __restrict__ psum) {
  const int bid = blockIdx.x;
  const int qt = 15 - (bid >> 8);        // heavy q-tiles dispatched first
  const int rem = bid & 255;
  const int bh = rem >> 2;
  const int s = rem & 3;
  const int tid = threadIdx.x;
  const int lane = tid & 63, w = tid >> 6;
  const int lr = lane & 15, lg = lane >> 4;
  const int qbase = qt * LSE_QT + w * 32;

  const bf16* qp = qh + ((size_t)bh * T_ + qbase) * D_;
  short8 qf[2][2];
#pragma unroll
  for (int f = 0; f < 2; ++f)
#pragma unroll
    for (int h = 0; h < 2; ++h)
      qf[f][h] = *(const short8*)&qp[(size_t)(f * 16 + lr) * D_ + h * 32 + lg * 8];

  float l[2][4];
#pragma unroll
  for (int f = 0; f < 2; ++f)
#pragma unroll
    for (int r = 0; r < 4; ++r) l[f][r] = 0.0f;

  const bf16* kbase = kh + (size_t)bh * T_ * D_;
  const int nfull = qbase >> 6;  // tiles 0..nfull-1 unmasked; tile nfull is diagonal

  for (int kt = s; kt < nfull; kt += 4) {
    const bf16* kp = kbase + (size_t)kt * 64 * D_;
    f32x4 sc[2][4];
#pragma unroll
    for (int f = 0; f < 2; ++f)
#pragma unroll
      for (int j = 0; j < 4; ++j) sc[f][j] = (f32x4)(0.0f);
#pragma unroll
    for (int j = 0; j < 4; ++j) {
      short8 k0 = *(const short8*)&kp[(size_t)(j * 16 + lr) * D_ + lg * 8];
      short8 k1 = *(const short8*)&kp[(size_t)(j * 16 + lr) * D_ + 32 + lg * 8];
      sc[0][j] = __builtin_amdgcn_mfma_f32_16x16x32_bf16(qf[0][0], k0, sc[0][j], 0, 0, 0);
      sc[0][j] = __builtin_amdgcn_mfma_f32_16x16x32_bf16(qf[0][1], k1, sc[0][j], 0, 0, 0);
      sc[1][j] = __builtin_amdgcn_mfma_f32_16x16x32_bf16(qf[1][0], k0, sc[1][j], 0, 0, 0);
      sc[1][j] = __builtin_amdgcn_mfma_f32_16x16x32_bf16(qf[1][1], k1, sc[1][j], 0, 0, 0);
    }
#pragma unroll
    for (int f = 0; f < 2; ++f)
#pragma unroll
      for (int j = 0; j < 4; ++j)
#pragma unroll
        for (int r = 0; r < 4; ++r) l[f][r] += __expf(sc[f][j][r]);
  }

  // diagonal (partial) tile: owned by split s == nfull % 4
  if ((nfull & 3) == s) {
    const int dkt = nfull;
    const bf16* kp = kbase + (size_t)dkt * 64 * D_;
    f32x4 sc[2][4];
#pragma unroll
    for (int f = 0; f < 2; ++f)
#pragma unroll
      for (int j = 0; j < 4; ++j) sc[f][j] = (f32x4)(0.0f);
#pragma unroll
    for (int j = 0; j < 4; ++j) {
      short8 k0 = *(const short8*)&kp[(size_t)(j * 16 + lr) * D_ + lg * 8];
      short8 k1 = *(const short8*)&kp[(size_t)(j * 16 + lr) * D_ + 32 + lg * 8];
      sc[0][j] = __builtin_amdgcn_mfma_f32_16x16x32_bf16(qf[0][0], k0, sc[0][j], 0, 0, 0);
      sc[0][j] = __builtin_amdgcn_mfma_f32_16x16x32_bf16(qf[0][1], k1, sc[0][j], 0, 0, 0);
      sc[1][j] = __builtin_amdgcn_mfma_f32_16x16x32_bf16(qf[1][0], k0, sc[1][j], 0, 0, 0);
      sc[1][j] = __builtin_amdgcn_mfma_f32_16x16x32_bf16(qf[1][1], k1, sc[1][j], 0, 0, 0);
    }
#pragma unroll
    for (int f = 0; f < 2; ++f)
#pragma unroll
      for (int j = 0; j < 4; ++j)
#pragma unroll
        for (int r = 0; r < 4; ++r) {
          int qrow = qbase + f * 16 + lg * 4 + r;
          int key = dkt * 64 + j * 16 + lr;
          float a = (key <= qrow) ? sc[f][j][r] : -INFINITY;
          l[f][r] += __expf(a);  // __expf(-inf) == 0
        }
  }

  // cross-lane (lr) reduce and store partial sum (always write, even zero)
#pragma unroll
  for (int f = 0; f < 2; ++f)
#pragma unroll
    for (int r = 0; r < 4; ++r) {
      float v = l[f][r];
      v += __shfl_xor(v, 1);
      v += __shfl_xor(v, 2);
      v += __shfl_xor(v, 4);
      v += __shfl_xor(v, 8);
      if (lr == 0)
        psum[(size_t)s * PS_ + (size_t)bh * T_ + qbase + f * 16 + lg * 4 + r] = v;
    }
}

// ---------------- final: out[b,t] = sum_h log(sum_s psum) * cw[h] ----------------
__global__ void proj_out(const float* __restrict__ psum, const float* __restrict__ Wp,
                         float* __restrict__ out) {
  __shared__ float cw[H_];
  int tid = threadIdx.x;
  if (tid < H_) {
    float s = 0.0f;
    for (int g = 0; g < H_; ++g) s += Wp[g * H_ + tid];
    cw[tid] = s;
  }
  __syncthreads();
  int idx = blockIdx.x * blockDim.x + tid;  // b*T + t
  int b = idx >> 11, t = idx & (T_ - 1);
  float acc = 0.0f;
#pragma unroll
  for (int h = 0; h < H_; ++h) {
    size_t base = ((size_t)(b * H_ + h) * T_) + t;
    float v = psum[base] + psum[PS_ + base] + psum[2 * (size_t)PS_ + base] +
              psum[3 * (size_t)PS_ + base];
    acc += __logf(v) * cw[h];
  }
  out[idx] = acc;
}

// ---------------- launch ----------------
extern "C" void kernel_launch(void* const* d_in, const int* in_sizes, int n_in,
                              void* d_out, int out_size, void* d_ws, size_t ws_size,
                              hipStream_t stream) {
  (void)in_sizes; (void)n_in; (void)out_size; (void)ws_size;
  const float* g  = (const float*)d_in[0];   // [B,T,E] fp32
  const float* Wl = (const float*)d_in[1];   // [2E,E] fp32
  const float* Wp = (const float*)d_in[2];   // [H,H] fp32
  float* out = (float*)d_out;                // [B*T] fp32

  char* ws = (char*)d_ws;
  size_t off = 0;
  bf16* g_bf  = (bf16*)(ws + off); off += (size_t)Mtot * K_ * 2;
  bf16* wl_bf = (bf16*)(ws + off); off += (size_t)N2 * K_ * 2;
  bf16* qh    = (bf16*)(ws + off); off += (size_t)B_ * H_ * T_ * D_ * 2;
  bf16* kh    = (bf16*)(ws + off); off += (size_t)B_ * H_ * T_ * D_ * 2;
  float* psum = (float*)(ws + off);          // 4 planes x 512KB = 2MB

  cast_f32_to_bf16<<<2048, 256, 0, stream>>>(g,  (ushort*)g_bf,  (Mtot * K_) / 4);
  cast_f32_to_bf16<<<512,  256, 0, stream>>>(Wl, (ushort*)wl_bf, (N2 * K_) / 4);

  lift_gemm<<<dim3(Mtot / 128, N2 / 128), 256, 0, stream>>>(g_bf, wl_bf, qh, kh);

  attn_lse<<<4096, 256, 0, stream>>>(qh, kh, psum);

  proj_out<<<(B_ * T_) / 256, 256, 0, stream>>>(psum, Wp, out);
}

// Round 5
// 99.174 us; speedup vs baseline: 1.6420x; 1.3905x over previous
//
#include <hip/hip_runtime.h>
#include <hip/hip_bf16.h>

#define B_ 4
#define T_ 2048
#define E_ 1024
#define H_ 16
#define D_ 64
#define Mtot 8192
#define N2 2048
#define K_ 1024
#define PS_ (B_ * H_ * T_)   // one psum plane

typedef __attribute__((ext_vector_type(8))) short short8;
typedef __attribute__((ext_vector_type(4))) float f32x4;
using bf16 = __hip_bfloat16;

__device__ __forceinline__ void async_copy16(const void* g, void* l) {
  __builtin_amdgcn_global_load_lds(
      (const __attribute__((address_space(1))) unsigned int*)g,
      (__attribute__((address_space(3))) unsigned int*)l, 16, 0, 0);
}

// ---------------- cast fp32 -> bf16 (vectorized) ----------------
__global__ void cast_f32_to_bf16(const float* __restrict__ in, ushort* __restrict__ out, int n4) {
  int stride = gridDim.x * blockDim.x;
  for (int i = blockIdx.x * blockDim.x + threadIdx.x; i < n4; i += stride) {
    float4 v = reinterpret_cast<const float4*>(in)[i];
    bf16 a = __float2bfloat16(v.x), b = __float2bfloat16(v.y);
    bf16 c = __float2bfloat16(v.z), d = __float2bfloat16(v.w);
    ushort4 o = make_ushort4(*(ushort*)&a, *(ushort*)&b, *(ushort*)&c, *(ushort*)&d);
    reinterpret_cast<ushort4*>(out)[i] = o;
  }
}

// ---------------- lift GEMM (m97 structure, kept from R3) ----------------
#define GBK 64

__launch_bounds__(256)
__global__ void lift_gemm(const bf16* __restrict__ A, const bf16* __restrict__ Bm,
                          bf16* __restrict__ qh, bf16* __restrict__ kh) {
  __shared__ __align__(16) bf16 sA[128 * GBK];
  __shared__ __align__(16) bf16 sB[128 * GBK];
  const int m0 = blockIdx.x * 128;
  const int n0 = blockIdx.y * 128;
  const int tid = threadIdx.x;
  const int lane = tid & 63, w = tid >> 6;
  const int wr = w >> 1, wc = w & 1;
  const int lr = lane & 15, lg = lane >> 4;

  f32x4 acc[4][4];
#pragma unroll
  for (int i = 0; i < 4; ++i)
#pragma unroll
    for (int j = 0; j < 4; ++j) acc[i][j] = (f32x4)(0.0f);

  const char* Ab = (const char*)A;
  const char* Bb = (const char*)Bm;

  for (int k0 = 0; k0 < K_; k0 += GBK) {
    __syncthreads();
#pragma unroll
    for (int it = 0; it < 4; ++it) {
      const int o = ((w * 4 + it) << 10) | (lane << 4);
      const int lin = o ^ (((o >> 7) & 7) << 4);
      const int r = lin >> 7, cb = lin & 127;
      const size_t gof = ((size_t)(m0 + r) * K_ + k0) * 2 + cb;
      const size_t gof_b = ((size_t)(n0 + r) * K_ + k0) * 2 + cb;
      async_copy16(Ab + gof, (char*)sA + ((w * 4 + it) << 10));
      async_copy16(Bb + gof_b, (char*)sB + ((w * 4 + it) << 10));
    }
    __syncthreads();

#pragma unroll
    for (int h = 0; h < 2; ++h) {
      short8 af[4], bfr[4];
#pragma unroll
      for (int i = 0; i < 4; ++i) {
        int row = wr * 64 + i * 16 + lr;
        int off = (row << 7) + (h << 6) + (lg << 4);
        off ^= ((row & 7) << 4);
        af[i] = *(const short8*)((const char*)sA + off);
      }
#pragma unroll
      for (int j = 0; j < 4; ++j) {
        int row = wc * 64 + j * 16 + lr;
        int off = (row << 7) + (h << 6) + (lg << 4);
        off ^= ((row & 7) << 4);
        bfr[j] = *(const short8*)((const char*)sB + off);
      }
#pragma unroll
      for (int i = 0; i < 4; ++i)
#pragma unroll
        for (int j = 0; j < 4; ++j)
          acc[i][j] = __builtin_amdgcn_mfma_f32_16x16x32_bf16(af[i], bfr[j], acc[i][j], 0, 0, 0);
    }
  }

#pragma unroll
  for (int i = 0; i < 4; ++i) {
#pragma unroll
    for (int j = 0; j < 4; ++j) {
#pragma unroll
      for (int r = 0; r < 4; ++r) {
        int m = m0 + wr * 64 + i * 16 + lg * 4 + r;
        int f = n0 + wc * 64 + j * 16 + lr;
        bf16 bv = __float2bfloat16(acc[i][j][r]);
        int b = m >> 11, t = m & (T_ - 1);
        int hh = (f & (E_ - 1)) >> 6, d = f & (D_ - 1);
        bf16* dst = (f < E_) ? qh : kh;
        dst[((((size_t)b * H_ + hh) * T_) + t) * D_ + d] = bv;
      }
    }
  }
}

// ---------------- causal LSE: 4-way KV split + block-shared LDS K tiles ----------
// Grid 4096 = (qt desc) x (bh) x (s in 0..3). Block = 4 waves, wave owns 32 q rows.
// K tiles staged once per block in double-buffered swizzled LDS; all 4 waves share.
#define LSE_QT 128

__launch_bounds__(256)
__global__ void attn_lse(const bf16* __restrict__ qh, const bf16* __restrict__ kh,
                         float* __restrict__ psum) {
  __shared__ __align__(16) bf16 sK[2][64 * 64];  // 2 x 8KB, physical (swizzled)
  const int bid = blockIdx.x;
  const int qt = 15 - (bid >> 8);        // heavy q-tiles dispatched first
  const int rem = bid & 255;
  const int bh = rem >> 2;
  const int s = rem & 3;
  const int tid = threadIdx.x;
  const int lane = tid & 63, w = tid >> 6;
  const int lr = lane & 15, lg = lane >> 4;
  const int qbase = qt * LSE_QT + w * 32;

  const bf16* qp = qh + ((size_t)bh * T_ + qbase) * D_;
  short8 qf[2][2];
#pragma unroll
  for (int f = 0; f < 2; ++f)
#pragma unroll
    for (int h = 0; h < 2; ++h)
      qf[f][h] = *(const short8*)&qp[(size_t)(f * 16 + lr) * D_ + h * 32 + lg * 8];

  float l[2][4];
#pragma unroll
  for (int f = 0; f < 2; ++f)
#pragma unroll
    for (int r = 0; r < 4; ++r) l[f][r] = 0.0f;

  const char* kbase = (const char*)(kh + (size_t)bh * T_ * D_);
  const int nfullw = qt * 2 + (w >> 1);  // wave's diagonal tile index
  const int maxk = qt * 2 + 1;           // largest tile any wave needs (inclusive)
  const int nt = (s <= maxk) ? ((maxk - s) >> 2) + 1 : 0;

  // stage tile kt into LDS buffer bi: linear dest + inverse-swizzled source
#define STAGE_K(bi, kt_)                                                      \
  do {                                                                        \
    const char* kp_ = kbase + (size_t)(kt_) * (64 * D_ * 2);                  \
    _Pragma("unroll") for (int it = 0; it < 2; ++it) {                        \
      const int o = ((w * 2 + it) << 10) | (lane << 4);                       \
      const int lin = o ^ (((o >> 7) & 7) << 4);                              \
      async_copy16(kp_ + lin, (char*)&sK[bi][0] + ((w * 2 + it) << 10));      \
    }                                                                         \
  } while (0)

  int cur = 0;
  if (nt > 0) STAGE_K(0, s);
  for (int i = 0; i < nt; ++i) {
    __syncthreads();                         // tile i staged (drains vmcnt)
    if (i + 1 < nt) STAGE_K(cur ^ 1, s + 4 * (i + 1));  // prefetch next
    const int kt = s + 4 * i;
    if (kt <= nfullw) {
      const char* kb = (const char*)&sK[cur][0];
      short8 kf[4][2];
#pragma unroll
      for (int j = 0; j < 4; ++j) {
        int row = j * 16 + lr;
        int sw = ((row & 7) << 4);
        kf[j][0] = *(const short8*)(kb + (((row << 7) | (lg << 4)) ^ sw));
        kf[j][1] = *(const short8*)(kb + (((row << 7) | 64 | (lg << 4)) ^ sw));
      }
      f32x4 sc[2][4];
#pragma unroll
      for (int f = 0; f < 2; ++f)
#pragma unroll
        for (int j = 0; j < 4; ++j) sc[f][j] = (f32x4)(0.0f);
#pragma unroll
      for (int j = 0; j < 4; ++j) {
        sc[0][j] = __builtin_amdgcn_mfma_f32_16x16x32_bf16(qf[0][0], kf[j][0], sc[0][j], 0, 0, 0);
        sc[0][j] = __builtin_amdgcn_mfma_f32_16x16x32_bf16(qf[0][1], kf[j][1], sc[0][j], 0, 0, 0);
        sc[1][j] = __builtin_amdgcn_mfma_f32_16x16x32_bf16(qf[1][0], kf[j][0], sc[1][j], 0, 0, 0);
        sc[1][j] = __builtin_amdgcn_mfma_f32_16x16x32_bf16(qf[1][1], kf[j][1], sc[1][j], 0, 0, 0);
      }
      if (kt < nfullw) {
#pragma unroll
        for (int f = 0; f < 2; ++f)
#pragma unroll
          for (int j = 0; j < 4; ++j)
#pragma unroll
            for (int r = 0; r < 4; ++r) l[f][r] += __expf(sc[f][j][r]);
      } else {
#pragma unroll
        for (int f = 0; f < 2; ++f)
#pragma unroll
          for (int j = 0; j < 4; ++j)
#pragma unroll
            for (int r = 0; r < 4; ++r) {
              int qrow = qbase + f * 16 + lg * 4 + r;
              int key = kt * 64 + j * 16 + lr;
              float a = (key <= qrow) ? sc[f][j][r] : -INFINITY;
              l[f][r] += __expf(a);  // __expf(-inf) == 0
            }
      }
    }
    __syncthreads();                         // all waves done reading sK[cur]
    cur ^= 1;
  }

  // cross-lane (lr) reduce and store partial sum (always write, even zero)
#pragma unroll
  for (int f = 0; f < 2; ++f)
#pragma unroll
    for (int r = 0; r < 4; ++r) {
      float v = l[f][r];
      v += __shfl_xor(v, 1);
      v += __shfl_xor(v, 2);
      v += __shfl_xor(v, 4);
      v += __shfl_xor(v, 8);
      if (lr == 0)
        psum[(size_t)s * PS_ + (size_t)bh * T_ + qbase + f * 16 + lg * 4 + r] = v;
    }
}

// ---------------- final: out[b,t] = sum_h log(sum_s psum) * cw[h] ----------------
__global__ void proj_out(const float* __restrict__ psum, const float* __restrict__ Wp,
                         float* __restrict__ out) {
  __shared__ float cw[H_];
  int tid = threadIdx.x;
  if (tid < H_) {
    float s = 0.0f;
    for (int g = 0; g < H_; ++g) s += Wp[g * H_ + tid];
    cw[tid] = s;
  }
  __syncthreads();
  int idx = blockIdx.x * blockDim.x + tid;  // b*T + t
  int b = idx >> 11, t = idx & (T_ - 1);
  float acc = 0.0f;
#pragma unroll
  for (int h = 0; h < H_; ++h) {
    size_t base = ((size_t)(b * H_ + h) * T_) + t;
    float v = psum[base] + psum[PS_ + base] + psum[2 * (size_t)PS_ + base] +
              psum[3 * (size_t)PS_ + base];
    acc += __logf(v) * cw[h];
  }
  out[idx] = acc;
}

// ---------------- launch ----------------
extern "C" void kernel_launch(void* const* d_in, const int* in_sizes, int n_in,
                              void* d_out, int out_size, void* d_ws, size_t ws_size,
                              hipStream_t stream) {
  (void)in_sizes; (void)n_in; (void)out_size; (void)ws_size;
  const float* g  = (const float*)d_in[0];   // [B,T,E] fp32
  const float* Wl = (const float*)d_in[1];   // [2E,E] fp32
  const float* Wp = (const float*)d_in[2];   // [H,H] fp32
  float* out = (float*)d_out;                // [B*T] fp32

  char* ws = (char*)d_ws;
  size_t off = 0;
  bf16* g_bf  = (bf16*)(ws + off); off += (size_t)Mtot * K_ * 2;
  bf16* wl_bf = (bf16*)(ws + off); off += (size_t)N2 * K_ * 2;
  bf16* qh    = (bf16*)(ws + off); off += (size_t)B_ * H_ * T_ * D_ * 2;
  bf16* kh    = (bf16*)(ws + off); off += (size_t)B_ * H_ * T_ * D_ * 2;
  float* psum = (float*)(ws + off);          // 4 planes x 512KB = 2MB

  cast_f32_to_bf16<<<2048, 256, 0, stream>>>(g,  (ushort*)g_bf,  (Mtot * K_) / 4);
  cast_f32_to_bf16<<<512,  256, 0, stream>>>(Wl, (ushort*)wl_bf, (N2 * K_) / 4);

  lift_gemm<<<dim3(Mtot / 128, N2 / 128), 256, 0, stream>>>(g_bf, wl_bf, qh, kh);

  attn_lse<<<4096, 256, 0, stream>>>(qh, kh, psum);

  proj_out<<<(B_ * T_) / 256, 256, 0, stream>>>(psum, Wp, out);
}

// Round 6
// 92.009 us; speedup vs baseline: 1.7699x; 1.0779x over previous
//
#include <hip/hip_runtime.h>
#include <hip/hip_bf16.h>

#define B_ 4
#define T_ 2048
#define E_ 1024
#define H_ 16
#define D_ 64
#define Mtot 8192
#define N2 2048
#define K_ 1024
#define PS_ (B_ * H_ * T_)   // one psum plane
#define NKT 16               // K / 64

typedef __attribute__((ext_vector_type(8))) short short8;
typedef __attribute__((ext_vector_type(4))) float f32x4;
using bf16 = __hip_bfloat16;

__device__ __forceinline__ void async_copy16(const void* g, void* l) {
  __builtin_amdgcn_global_load_lds(
      (const __attribute__((address_space(1))) unsigned int*)g,
      (__attribute__((address_space(3))) unsigned int*)l, 16, 0, 0);
}

// ---------------- cast fp32 -> bf16 (vectorized) ----------------
__global__ void cast_f32_to_bf16(const float* __restrict__ in, ushort* __restrict__ out, int n4) {
  int stride = gridDim.x * blockDim.x;
  for (int i = blockIdx.x * blockDim.x + threadIdx.x; i < n4; i += stride) {
    float4 v = reinterpret_cast<const float4*>(in)[i];
    bf16 a = __float2bfloat16(v.x), b = __float2bfloat16(v.y);
    bf16 c = __float2bfloat16(v.z), d = __float2bfloat16(v.w);
    ushort4 o = make_ushort4(*(ushort*)&a, *(ushort*)&b, *(ushort*)&c, *(ushort*)&d);
    reinterpret_cast<ushort4*>(out)[i] = o;
  }
}

// ---------------- lift GEMM: 256x256 tile, 4-phase counted-vmcnt pipeline ------
// C[m][f] = sum_e A[m][e] * Bm[f][e].  8 waves (2M x 4N), each owns 128x64 of C.
// LDS: 8 circular half-tile slots (128 rows x 64 cols bf16 = 16KB each) = 128KB.
// K-tile kt lives in slots (kt&1)*4 + {A0,A1,B0,B1}. Stages run one K-tile ahead:
// kt+1's A-halves issue at kt.q0, B-halves at kt.q1; gate = vmcnt(4) at q0.
#define MFMA_BF16(a, b, c) __builtin_amdgcn_mfma_f32_16x16x32_bf16(a, b, c, 0, 0, 0)

__launch_bounds__(512, 2)
__global__ void lift_gemm(const bf16* __restrict__ A, const bf16* __restrict__ Bm,
                          bf16* __restrict__ qh, bf16* __restrict__ kh) {
  __shared__ __align__(16) char sL[8][16384];
  const int bid = blockIdx.x;
  const int swz = ((bid & 7) << 5) | (bid >> 3);  // XCD-chunked (256 = 8*32)
  const int m0 = (swz >> 3) * 256;
  const int n0 = (swz & 7) * 256;
  const int tid = threadIdx.x;
  const int lane = tid & 63, w = tid >> 6;
  const int wm = w >> 2, wn = w & 3;
  const int lr = lane & 15, lg = lane >> 4;

  f32x4 acc[8][4];
#pragma unroll
  for (int i = 0; i < 8; ++i)
#pragma unroll
    for (int j = 0; j < 4; ++j) acc[i][j] = (f32x4)(0.0f);

  // stage one half-tile (128 rows x 64 cols) into slot: linear LDS dest,
  // inverse-swizzled global source (involution: byte ^= ((row&7)<<4)).
  auto stage_half = [&](int slot, const bf16* gsrc, int Rbase, int kcol) {
#pragma unroll
    for (int it = 0; it < 2; ++it) {
      const int o = ((it * 512 + tid) << 4);
      const int lin = o ^ (((o >> 7) & 7) << 4);
      const int r = lin >> 7, cb = lin & 127;
      async_copy16((const char*)gsrc + ((size_t)(Rbase + r) * K_ + kcol) * 2 + cb,
                   &sL[slot][o]);
    }
  };
  // swizzled frag read: row in [0,128), khalf in {0,1}
  auto rd = [&](int slot, int row, int khalf) -> short8 {
    int off = (row << 7) + (khalf << 6) + (lg << 4);
    off ^= (row & 7) << 4;
    return *(const short8*)&sL[slot][off];
  };

  // prologue: K-tile 0 -> slots 0..3
  stage_half(0, A, m0, 0);
  stage_half(1, A, m0 + 128, 0);
  stage_half(2, Bm, n0, 0);
  stage_half(3, Bm, n0 + 128, 0);

  short8 af[4][2], bf0[2][2], bf1[2][2];

  for (int kt = 0; kt < NKT; ++kt) {
    const int cb = (kt & 1) << 2;
    const int nb = cb ^ 4;
    const int kcol = (kt + 1) * 64;
    const int aslot = cb + wm;
    const int bslot = cb + 2 + (wn >> 1);
    const int brow = (wn & 1) * 64;

    // ---- phase 0: stage next A halves; gate; MFMA quadrant (mi0-3 x ni0-1) ----
    if (kt + 1 < NKT) {
      stage_half(nb + 0, A, m0, kcol);
      stage_half(nb + 1, A, m0 + 128, kcol);
      asm volatile("s_waitcnt vmcnt(4)" ::: "memory");
    } else {
      asm volatile("s_waitcnt vmcnt(0)" ::: "memory");
    }
    __builtin_amdgcn_sched_barrier(0);
    __builtin_amdgcn_s_barrier();
#pragma unroll
    for (int i = 0; i < 4; ++i) {
      af[i][0] = rd(aslot, i * 16 + lr, 0);
      af[i][1] = rd(aslot, i * 16 + lr, 1);
    }
#pragma unroll
    for (int j = 0; j < 2; ++j) {
      bf0[j][0] = rd(bslot, brow + j * 16 + lr, 0);
      bf0[j][1] = rd(bslot, brow + j * 16 + lr, 1);
    }
    __builtin_amdgcn_s_setprio(1);
#pragma unroll
    for (int i = 0; i < 4; ++i)
#pragma unroll
      for (int j = 0; j < 2; ++j) {
        acc[i][j] = MFMA_BF16(af[i][0], bf0[j][0], acc[i][j]);
        acc[i][j] = MFMA_BF16(af[i][1], bf0[j][1], acc[i][j]);
      }
    __builtin_amdgcn_s_setprio(0);
    __builtin_amdgcn_sched_barrier(0);
    __builtin_amdgcn_s_barrier();

    // ---- phase 1: stage next B halves; MFMA quadrant (mi0-3 x ni2-3) ----
    if (kt + 1 < NKT) {
      stage_half(nb + 2, Bm, n0, kcol);
      stage_half(nb + 3, Bm, n0 + 128, kcol);
    }
#pragma unroll
    for (int j = 0; j < 2; ++j) {
      bf1[j][0] = rd(bslot, brow + (j + 2) * 16 + lr, 0);
      bf1[j][1] = rd(bslot, brow + (j + 2) * 16 + lr, 1);
    }
    __builtin_amdgcn_sched_barrier(0);
    __builtin_amdgcn_s_barrier();
    __builtin_amdgcn_s_setprio(1);
#pragma unroll
    for (int i = 0; i < 4; ++i)
#pragma unroll
      for (int j = 0; j < 2; ++j) {
        acc[i][j + 2] = MFMA_BF16(af[i][0], bf1[j][0], acc[i][j + 2]);
        acc[i][j + 2] = MFMA_BF16(af[i][1], bf1[j][1], acc[i][j + 2]);
      }
    __builtin_amdgcn_s_setprio(0);
    __builtin_amdgcn_sched_barrier(0);
    __builtin_amdgcn_s_barrier();

    // ---- phase 2: MFMA quadrant (mi4-7 x ni0-1) ----
#pragma unroll
    for (int i = 0; i < 4; ++i) {
      af[i][0] = rd(aslot, (i + 4) * 16 + lr, 0);
      af[i][1] = rd(aslot, (i + 4) * 16 + lr, 1);
    }
    __builtin_amdgcn_sched_barrier(0);
    __builtin_amdgcn_s_barrier();
    __builtin_amdgcn_s_setprio(1);
#pragma unroll
    for (int i = 0; i < 4; ++i)
#pragma unroll
      for (int j = 0; j < 2; ++j) {
        acc[i + 4][j] = MFMA_BF16(af[i][0], bf0[j][0], acc[i + 4][j]);
        acc[i + 4][j] = MFMA_BF16(af[i][1], bf0[j][1], acc[i + 4][j]);
      }
    __builtin_amdgcn_s_setprio(0);
    __builtin_amdgcn_sched_barrier(0);
    __builtin_amdgcn_s_barrier();

    // ---- phase 3: MFMA quadrant (mi4-7 x ni2-3) ----
    __builtin_amdgcn_s_setprio(1);
#pragma unroll
    for (int i = 0; i < 4; ++i)
#pragma unroll
      for (int j = 0; j < 2; ++j) {
        acc[i + 4][j + 2] = MFMA_BF16(af[i][0], bf1[j][0], acc[i + 4][j + 2]);
        acc[i + 4][j + 2] = MFMA_BF16(af[i][1], bf1[j][1], acc[i + 4][j + 2]);
      }
    __builtin_amdgcn_s_setprio(0);
    __builtin_amdgcn_sched_barrier(0);
    __builtin_amdgcn_s_barrier();
  }

  // epilogue: scatter bf16 into qh/kh [b][h][t][d]
#pragma unroll
  for (int mi = 0; mi < 8; ++mi) {
#pragma unroll
    for (int ni = 0; ni < 4; ++ni) {
#pragma unroll
      for (int r = 0; r < 4; ++r) {
        int m = m0 + wm * 128 + mi * 16 + lg * 4 + r;
        int f = n0 + wn * 64 + ni * 16 + lr;
        bf16 bv = __float2bfloat16(acc[mi][ni][r]);
        int b = m >> 11, t = m & (T_ - 1);
        int hh = (f & (E_ - 1)) >> 6, d = f & (D_ - 1);
        bf16* dst = (f < E_) ? qh : kh;
        dst[((((size_t)b * H_ + hh) * T_) + t) * D_ + d] = bv;
      }
    }
  }
}

// ---------------- causal LSE: 4-way KV split + block-shared LDS K tiles ----------
#define LSE_QT 128

__launch_bounds__(256)
__global__ void attn_lse(const bf16* __restrict__ qh, const bf16* __restrict__ kh,
                         float* __restrict__ psum) {
  __shared__ __align__(16) bf16 sK[2][64 * 64];  // 2 x 8KB, physical (swizzled)
  const int bid = blockIdx.x;
  const int qt = 15 - (bid >> 8);        // heavy q-tiles dispatched first
  const int rem = bid & 255;
  const int bh = rem >> 2;
  const int s = rem & 3;
  const int tid = threadIdx.x;
  const int lane = tid & 63, w = tid >> 6;
  const int lr = lane & 15, lg = lane >> 4;
  const int qbase = qt * LSE_QT + w * 32;

  const bf16* qp = qh + ((size_t)bh * T_ + qbase) * D_;
  short8 qf[2][2];
#pragma unroll
  for (int f = 0; f < 2; ++f)
#pragma unroll
    for (int h = 0; h < 2; ++h)
      qf[f][h] = *(const short8*)&qp[(size_t)(f * 16 + lr) * D_ + h * 32 + lg * 8];

  float l[2][4];
#pragma unroll
  for (int f = 0; f < 2; ++f)
#pragma unroll
    for (int r = 0; r < 4; ++r) l[f][r] = 0.0f;

  const char* kbase = (const char*)(kh + (size_t)bh * T_ * D_);
  const int nfullw = qt * 2 + (w >> 1);  // wave's diagonal tile index
  const int maxk = qt * 2 + 1;           // largest tile any wave needs (inclusive)
  const int nt = (s <= maxk) ? ((maxk - s) >> 2) + 1 : 0;

#define STAGE_K(bi, kt_)                                                      \
  do {                                                                        \
    const char* kp_ = kbase + (size_t)(kt_) * (64 * D_ * 2);                  \
    _Pragma("unroll") for (int it = 0; it < 2; ++it) {                        \
      const int o = ((w * 2 + it) << 10) | (lane << 4);                       \
      const int lin = o ^ (((o >> 7) & 7) << 4);                              \
      async_copy16(kp_ + lin, (char*)&sK[bi][0] + ((w * 2 + it) << 10));      \
    }                                                                         \
  } while (0)

  int cur = 0;
  if (nt > 0) STAGE_K(0, s);
  for (int i = 0; i < nt; ++i) {
    __syncthreads();                         // tile i staged (drains vmcnt)
    if (i + 1 < nt) STAGE_K(cur ^ 1, s + 4 * (i + 1));  // prefetch next
    const int kt = s + 4 * i;
    if (kt <= nfullw) {
      const char* kb = (const char*)&sK[cur][0];
      short8 kf[4][2];
#pragma unroll
      for (int j = 0; j < 4; ++j) {
        int row = j * 16 + lr;
        int sw = ((row & 7) << 4);
        kf[j][0] = *(const short8*)(kb + (((row << 7) | (lg << 4)) ^ sw));
        kf[j][1] = *(const short8*)(kb + (((row << 7) | 64 | (lg << 4)) ^ sw));
      }
      f32x4 sc[2][4];
#pragma unroll
      for (int f = 0; f < 2; ++f)
#pragma unroll
        for (int j = 0; j < 4; ++j) sc[f][j] = (f32x4)(0.0f);
#pragma unroll
      for (int j = 0; j < 4; ++j) {
        sc[0][j] = MFMA_BF16(qf[0][0], kf[j][0], sc[0][j]);
        sc[0][j] = MFMA_BF16(qf[0][1], kf[j][1], sc[0][j]);
        sc[1][j] = MFMA_BF16(qf[1][0], kf[j][0], sc[1][j]);
        sc[1][j] = MFMA_BF16(qf[1][1], kf[j][1], sc[1][j]);
      }
      if (kt < nfullw) {
#pragma unroll
        for (int f = 0; f < 2; ++f)
#pragma unroll
          for (int j = 0; j < 4; ++j)
#pragma unroll
            for (int r = 0; r < 4; ++r) l[f][r] += __expf(sc[f][j][r]);
      } else {
#pragma unroll
        for (int f = 0; f < 2; ++f)
#pragma unroll
          for (int j = 0; j < 4; ++j)
#pragma unroll
            for (int r = 0; r < 4; ++r) {
              int qrow = qbase + f * 16 + lg * 4 + r;
              int key = kt * 64 + j * 16 + lr;
              float a = (key <= qrow) ? sc[f][j][r] : -INFINITY;
              l[f][r] += __expf(a);  // __expf(-inf) == 0
            }
      }
    }
    __syncthreads();                         // all waves done reading sK[cur]
    cur ^= 1;
  }

  // cross-lane (lr) reduce and store partial sum (always write, even zero)
#pragma unroll
  for (int f = 0; f < 2; ++f)
#pragma unroll
    for (int r = 0; r < 4; ++r) {
      float v = l[f][r];
      v += __shfl_xor(v, 1);
      v += __shfl_xor(v, 2);
      v += __shfl_xor(v, 4);
      v += __shfl_xor(v, 8);
      if (lr == 0)
        psum[(size_t)s * PS_ + (size_t)bh * T_ + qbase + f * 16 + lg * 4 + r] = v;
    }
}

// ---------------- final: out[b,t] = sum_h log(sum_s psum) * cw[h] ----------------
__global__ void proj_out(const float* __restrict__ psum, const float* __restrict__ Wp,
                         float* __restrict__ out) {
  __shared__ float cw[H_];
  int tid = threadIdx.x;
  if (tid < H_) {
    float s = 0.0f;
    for (int g = 0; g < H_; ++g) s += Wp[g * H_ + tid];
    cw[tid] = s;
  }
  __syncthreads();
  int idx = blockIdx.x * blockDim.x + tid;  // b*T + t
  int b = idx >> 11, t = idx & (T_ - 1);
  float acc = 0.0f;
#pragma unroll
  for (int h = 0; h < H_; ++h) {
    size_t base = ((size_t)(b * H_ + h) * T_) + t;
    float v = psum[base] + psum[PS_ + base] + psum[2 * (size_t)PS_ + base] +
              psum[3 * (size_t)PS_ + base];
    acc += __logf(v) * cw[h];
  }
  out[idx] = acc;
}

// ---------------- launch ----------------
extern "C" void kernel_launch(void* const* d_in, const int* in_sizes, int n_in,
                              void* d_out, int out_size, void* d_ws, size_t ws_size,
                              hipStream_t stream) {
  (void)in_sizes; (void)n_in; (void)out_size; (void)ws_size;
  const float* g  = (const float*)d_in[0];   // [B,T,E] fp32
  const float* Wl = (const float*)d_in[1];   // [2E,E] fp32
  const float* Wp = (const float*)d_in[2];   // [H,H] fp32
  float* out = (float*)d_out;                // [B*T] fp32

  char* ws = (char*)d_ws;
  size_t off = 0;
  bf16* g_bf  = (bf16*)(ws + off); off += (size_t)Mtot * K_ * 2;
  bf16* wl_bf = (bf16*)(ws + off); off += (size_t)N2 * K_ * 2;
  bf16* qh    = (bf16*)(ws + off); off += (size_t)B_ * H_ * T_ * D_ * 2;
  bf16* kh    = (bf16*)(ws + off); off += (size_t)B_ * H_ * T_ * D_ * 2;
  float* psum = (float*)(ws + off);          // 4 planes x 512KB = 2MB

  cast_f32_to_bf16<<<2048, 256, 0, stream>>>(g,  (ushort*)g_bf,  (Mtot * K_) / 4);
  cast_f32_to_bf16<<<512,  256, 0, stream>>>(Wl, (ushort*)wl_bf, (N2 * K_) / 4);

  lift_gemm<<<256, 512, 0, stream>>>(g_bf, wl_bf, qh, kh);

  attn_lse<<<4096, 256, 0, stream>>>(qh, kh, psum);

  proj_out<<<(B_ * T_) / 256, 256, 0, stream>>>(psum, Wp, out);
}